// Round 10
// baseline (4136.705 us; speedup 1.0000x reference)
//
#include <hip/hip_runtime.h>
#include <math.h>

// Problem constants (must match reference)
constexpr int B = 8, N = 32768, C = 3, H = 256, R = 64, NHID = 4;
constexpr int PTS   = 32;    // points per block
constexpr int BLOCK = 256;   // 32 o-lanes (8 outputs each) x 8 point-groups (4 pts each)
constexpr int PADA  = 260;   // LDS act row stride (multiple of 4 -> aligned float4)
constexpr int PADX  = 68;    // LDS XV row stride

// Workspace (floats), total ~3.07 MB:
//   ult : [NHID][B][R][H]  (U[l+1][o][r]*lat[b][r]) transposed [r][o] = 524,288
//   wT  : [NHID][H][H]     W_hid transposed [i][o] (bit-exact copy)   = 262,144
//   dw0 : [B][H][3]        layer-0 dW (np-exact, materialized)        =   6,144
//   fbe : [NHID+1][B][H]   FiLM bias                                  =  10,240
constexpr size_t OFS_ULT = 0;
constexpr size_t OFS_WT  = (size_t)NHID * B * R * H;
constexpr size_t OFS_DW0 = OFS_WT + (size_t)NHID * H * H;
constexpr size_t OFS_FBE = OFS_DW0 + (size_t)B * H * 3;

// ---------------------------------------------------------------------------
// fdlibm fp64 sine, error ~1e-16. Models numpy float32 sin as
// (float)sin((double)x). Used at LAYER 0 only (error gain 6.6e4 demands it).
// ---------------------------------------------------------------------------
__device__ __forceinline__ double sin_d(double x)
{
    const double INV_PIO2 = 6.36619772367581382433e-01;
    const double P1  = 1.57079632673412561417e+00;
    const double P1T = 6.07710050650619224932e-11;
    double fn = rint(x * INV_PIO2);
    int n = (int)fn;
    double r = fma(-fn, P1, x);
    r = fma(-fn, P1T, r);
    double z = r * r;
    double ps = fma(z, 1.58969099521155010221e-10, -2.50507602534068634195e-08);
    ps = fma(z, ps, 2.75573137070700676789e-06);
    ps = fma(z, ps, -1.98412698298579493134e-04);
    ps = fma(z, ps, 8.33333333332248946124e-03);
    ps = fma(z, ps, -1.66666666666666324348e-01);
    double s = fma(r * z, ps, r);
    double pc = fma(z, -1.13596475577881948265e-11, 2.08757232129817482790e-09);
    pc = fma(z, pc, -2.75573143513906633035e-07);
    pc = fma(z, pc, 2.48015872894767294178e-05);
    pc = fma(z, pc, -1.38888888888741095749e-03);
    pc = fma(z, pc, 4.16666666666666019037e-02);
    double c = fma(z * z, pc, fma(z, -0.5, 1.0));
    int k = n & 3;
    double v = (k & 1) ? c : s;
    return (k & 2) ? -v : v;
}

__device__ __forceinline__ float npsinf(float xf)
{
    return (float)sin_d((double)xf);
}

// ---------------------------------------------------------------------------
// Hybrid sine for hidden layers: fp64 Cody-Waite argument reduction + fp32
// polynomials. Diff vs (float)sin(double) ~1 ulp fp32. (unchanged from r9)
// ---------------------------------------------------------------------------
__device__ __forceinline__ float sinh32(float xf)
{
    const double INV_PIO2 = 6.36619772367581382433e-01;
    const double P1  = 1.57079632673412561417e+00;
    const double P1T = 6.07710050650619224932e-11;
    double xd = (double)xf;
    double fn = rint(xd * INV_PIO2);
    int n = (int)fn;
    double rd = fma(-fn, P1, xd);
    rd = fma(-fn, P1T, rd);
    float r = (float)rd;
    float z = r * r;
    float ps = fmaf(z, 2.7183114939898219e-06f, -1.9839334836096632e-04f);
    ps = fmaf(z, ps, 8.3333293e-03f);
    ps = fmaf(z, ps, -1.6666667e-01f);
    float s = fmaf(r * z, ps, r);
    float pc = fmaf(z, 2.4390448796277409e-05f, -1.3888781739898680e-03f);
    pc = fmaf(z, pc, 4.1666667e-02f);
    float c = fmaf(z * z, pc, fmaf(z, -0.5f, 1.0f));
    int k = n & 3;
    float v = (k & 1) ? c : s;
    return (k & 2) ? -v : v;
}

// ---------------------------------------------------------------------------
// Precompute (unchanged from r9): ult[l][b][r][o] = U[l+1][o][r]*lat[b][r],
// dw0 (layer-0 dW, np-exact), fbe (FiLM bias).
// ---------------------------------------------------------------------------
__global__ void precomp_np(const float* __restrict__ lat, const float* __restrict__ U,
                           const float* __restrict__ V0,
                           const float* __restrict__ HB,
                           float* __restrict__ ult, float* __restrict__ dw0,
                           float* __restrict__ fbe)
{
    int bi = blockIdx.x;
    int o  = threadIdx.x;
    if (bi < NHID * B) {
        int l = bi >> 3, b = bi & 7;
        const float* Uo = U + ((size_t)(l + 1) * H + o) * R;
        const float* lb = lat + b * R;
        float* dst = ult + (size_t)(l * B + b) * R * H;   // [r][o]
        #pragma unroll
        for (int r = 0; r < R; ++r)
            dst[(size_t)r * H + o] = Uo[r] * lb[r];       // rounded fp32 mul (np order)
    } else if (bi < NHID * B + B) {
        int b = bi - NHID * B;
        const float* Uo = U + (size_t)o * R;        // U[0][o][:]
        const float* lb = lat + b * R;
        float t[R];
        #pragma unroll
        for (int r = 0; r < R; ++r) t[r] = Uo[r] * lb[r];
        #pragma unroll
        for (int c = 0; c < C; ++c) {
            float acc = 0.f;
            #pragma unroll
            for (int r = 0; r < R; ++r) acc = fmaf(t[r], V0[c * R + r], acc);
            dw0[((size_t)b * H + o) * 3 + c] = acc;
        }
    } else {
        int b = bi - NHID * B - B;
        const float* lb = lat + b * R;
        for (int lidx = 0; lidx < NHID + 1; ++lidx) {
            const float* hb = HB + ((size_t)lidx * H + o) * R;
            float acc = 0.f;
            #pragma unroll
            for (int r = 0; r < R; ++r) acc = fmaf(lb[r], hb[r], acc);
            fbe[((size_t)lidx * B + b) * H + o] = acc;
        }
    }
}

// Pure bit-exact transpose: wT[l][i][o] = W_hid[l][o][i]
__global__ void transposeW(const float* __restrict__ Wh, float* __restrict__ wT)
{
    int li = blockIdx.x;           // l*H + i
    int o  = threadIdx.x;
    int l = li >> 8, i = li & 255;
    wT[(size_t)li * H + o] = Wh[((size_t)l * H + o) * H + i];
}

// ---------------------------------------------------------------------------
// np-replica forward, DS-traffic-halved mapping: og=tid&31 owns 8 outputs,
// pg=tid>>5 owns 4 points. Per i-step: 4 dual-broadcast ds_read_b128 feed
// 128 FMA (32 FMA/ds_read, 2x round 9). Per-(n,o) arithmetic BIT-IDENTICAL
// to rounds 6-9: lin = single fp32 acc, i ascending, fmaf over np-exact wT;
// delta factored (XV then ult, r ascending); ((lin+b)+delta)+fb, *30.0f,
// sin (L0 fp64, hidden hybrid).
// ---------------------------------------------------------------------------
__launch_bounds__(BLOCK)
__global__ void siren_np(const float* __restrict__ coords,
                         const float* __restrict__ Wf, const float* __restrict__ bf,
                         const float* __restrict__ bh,
                         const float* __restrict__ Wl, const float* __restrict__ bl,
                         const float* __restrict__ wT, const float* __restrict__ ult,
                         const float* __restrict__ Vh,
                         const float* __restrict__ dw0, const float* __restrict__ fbe,
                         float* __restrict__ out)
{
    __shared__ __align__(16) float abuf[PTS * PADA];   // 33,280 B
    __shared__ __align__(16) float xvbuf[PTS * PADX];  //  8,704 B
    __shared__ float cbuf[PTS * 3 + 1];
    const int tid = threadIdx.x;
    const int og = tid & 31, pg = tid >> 5;
    const int o0 = og * 8, pbase = pg * 4;
    const int p0 = blockIdx.x * PTS;          // global point base
    const int b  = p0 >> 15;                  // N = 2^15; all 32 pts same batch

    if (tid < PTS * 3) cbuf[tid] = coords[(size_t)p0 * 3 + tid];
    __syncthreads();

    // ---- layer 0 (same per-(n,o) arithmetic as rounds 6-9) ----
    {
        const float* fb0 = fbe + (size_t)(0 * B + b) * H;
        #pragma unroll
        for (int j = 0; j < 8; ++j) {
            const int o = o0 + j;
            const float wf0 = Wf[o * 3 + 0], wf1 = Wf[o * 3 + 1], wf2 = Wf[o * 3 + 2];
            const float* dwo = dw0 + ((size_t)b * H + o) * 3;
            const float dd0 = dwo[0], dd1 = dwo[1], dd2 = dwo[2];
            const float bo = bf[o], fo = fb0[o];
            #pragma unroll
            for (int k = 0; k < 4; ++k) {
                const float x0 = cbuf[(pbase + k) * 3 + 0];
                const float x1 = cbuf[(pbase + k) * 3 + 1];
                const float x2 = cbuf[(pbase + k) * 3 + 2];
                float lin = 0.f;
                lin = fmaf(x0, wf0, lin);
                lin = fmaf(x1, wf1, lin);
                lin = fmaf(x2, wf2, lin);
                lin = lin + bo;
                float dl = 0.f;
                dl = fmaf(x0, dd0, dl);
                dl = fmaf(x1, dd1, dl);
                dl = fmaf(x2, dd2, dl);
                float z = (lin + dl) + fo;
                abuf[(pbase + k) * PADA + o] = npsinf(30.0f * z);
            }
        }
    }
    __syncthreads();

    // ---- hidden layers ----
    for (int l = 0; l < NHID; ++l) {
        // phase A (unchanged from r9): XV[n][r] = sum_i act[n][i]*V[l][i][r]
        {
            const int xn = tid >> 3, r0 = (tid & 7) * 8;
            const float* Vb = Vh + (size_t)l * H * R;     // [i][r]
            float a8[8] = {0.f,0.f,0.f,0.f,0.f,0.f,0.f,0.f};
            for (int i0 = 0; i0 < H; i0 += 4) {
                float4 a4 = *(const float4*)(&abuf[xn * PADA + i0]);
                #pragma unroll
                for (int ii = 0; ii < 4; ++ii) {
                    const float ai = (&a4.x)[ii];
                    float4 va = *(const float4*)(Vb + (size_t)(i0 + ii) * R + r0);
                    float4 vb = *(const float4*)(Vb + (size_t)(i0 + ii) * R + r0 + 4);
                    a8[0] = fmaf(ai, va.x, a8[0]); a8[1] = fmaf(ai, va.y, a8[1]);
                    a8[2] = fmaf(ai, va.z, a8[2]); a8[3] = fmaf(ai, va.w, a8[3]);
                    a8[4] = fmaf(ai, vb.x, a8[4]); a8[5] = fmaf(ai, vb.y, a8[5]);
                    a8[6] = fmaf(ai, vb.z, a8[6]); a8[7] = fmaf(ai, vb.w, a8[7]);
                }
            }
            *(float4*)(&xvbuf[xn * PADX + r0])     = make_float4(a8[0], a8[1], a8[2], a8[3]);
            *(float4*)(&xvbuf[xn * PADX + r0 + 4]) = make_float4(a8[4], a8[5], a8[6], a8[7]);
        }
        __syncthreads();

        // phase B: delta (K=64 over ult, r ascending) ...
        float eacc[8][4];
        #pragma unroll
        for (int j = 0; j < 8; ++j)
            #pragma unroll
            for (int k = 0; k < 4; ++k) eacc[j][k] = 0.f;
        {
            const float4* UT4 = (const float4*)(ult + (size_t)(l * B + b) * R * H);
            for (int r0 = 0; r0 < R; r0 += 4) {
                float4 xv4[4];
                #pragma unroll
                for (int k = 0; k < 4; ++k)
                    xv4[k] = *(const float4*)(&xvbuf[(pbase + k) * PADX + r0]);
                #pragma unroll
                for (int rr = 0; rr < 4; ++rr) {       // r ASCENDING
                    const float4 ua = UT4[(size_t)(r0 + rr) * 64 + og * 2];
                    const float4 ub = UT4[(size_t)(r0 + rr) * 64 + og * 2 + 1];
                    const float uj[8] = {ua.x, ua.y, ua.z, ua.w, ub.x, ub.y, ub.z, ub.w};
                    #pragma unroll
                    for (int k = 0; k < 4; ++k) {
                        const float xv = (&xv4[k].x)[rr];
                        #pragma unroll
                        for (int j = 0; j < 8; ++j)
                            eacc[j][k] = fmaf(xv, uj[j], eacc[j][k]);
                    }
                }
            }
        }
        // ... then lin (K=256 over np-exact wT, i ascending, single acc)
        float lacc[8][4];
        #pragma unroll
        for (int j = 0; j < 8; ++j)
            #pragma unroll
            for (int k = 0; k < 4; ++k) lacc[j][k] = 0.f;
        {
            const float4* Wt4 = (const float4*)(wT + (size_t)l * H * H);
            for (int i0 = 0; i0 < H; i0 += 4) {
                // hoist all weight loads for this step (deeper in-flight)
                float4 wv[4][2];
                #pragma unroll
                for (int ii = 0; ii < 4; ++ii) {
                    wv[ii][0] = Wt4[(size_t)(i0 + ii) * 64 + og * 2];
                    wv[ii][1] = Wt4[(size_t)(i0 + ii) * 64 + og * 2 + 1];
                }
                float4 av[4];
                #pragma unroll
                for (int k = 0; k < 4; ++k)
                    av[k] = *(const float4*)(&abuf[(pbase + k) * PADA + i0]);
                #pragma unroll
                for (int ii = 0; ii < 4; ++ii) {        // i ASCENDING (np sgemm)
                    const float wj[8] = {wv[ii][0].x, wv[ii][0].y, wv[ii][0].z, wv[ii][0].w,
                                         wv[ii][1].x, wv[ii][1].y, wv[ii][1].z, wv[ii][1].w};
                    #pragma unroll
                    for (int k = 0; k < 4; ++k) {
                        const float ai = (&av[k].x)[ii];
                        #pragma unroll
                        for (int j = 0; j < 8; ++j)
                            lacc[j][k] = fmaf(ai, wj[j], lacc[j][k]);
                    }
                }
            }
        }
        __syncthreads();   // ALL reads of abuf/xvbuf complete before in-place writes
        {
            const float* be  = bh + (size_t)l * H;
            const float* fbl = fbe + (size_t)((l + 1) * B + b) * H;
            const float4 bo4a = *(const float4*)(be + o0);
            const float4 bo4b = *(const float4*)(be + o0 + 4);
            const float4 fo4a = *(const float4*)(fbl + o0);
            const float4 fo4b = *(const float4*)(fbl + o0 + 4);
            const float bo[8] = {bo4a.x, bo4a.y, bo4a.z, bo4a.w,
                                 bo4b.x, bo4b.y, bo4b.z, bo4b.w};
            const float fo[8] = {fo4a.x, fo4a.y, fo4a.z, fo4a.w,
                                 fo4b.x, fo4b.y, fo4b.z, fo4b.w};
            #pragma unroll
            for (int k = 0; k < 4; ++k) {
                float4 rv0, rv1;
                #pragma unroll
                for (int j = 0; j < 8; ++j) {
                    float z = ((lacc[j][k] + bo[j]) + eacc[j][k]) + fo[j];
                    float sv = sinh32(30.0f * z);
                    if (j < 4) (&rv0.x)[j] = sv; else (&rv1.x)[j - 4] = sv;
                }
                *(float4*)(&abuf[(pbase + k) * PADA + o0])     = rv0;
                *(float4*)(&abuf[(pbase + k) * PADA + o0 + 4]) = rv1;
            }
        }
        __syncthreads();   // writes visible before next layer's reads
    }

    // ---- final projection (gain ~1): same arithmetic as rounds 6-9 ----
    {
        const int pl = tid >> 3, q = tid & 7;
        const float* ar = abuf + pl * PADA + q * 32;
        const float* wl = Wl + q * 32;
        float s = 0.f;
        #pragma unroll 8
        for (int t = 0; t < 32; ++t) s = fmaf(ar[t], wl[t], s);
        s += __shfl_xor(s, 1);
        s += __shfl_xor(s, 2);
        s += __shfl_xor(s, 4);
        if (q == 0) out[p0 + pl] = s + bl[0];
    }
}

// ---------------------------------------------------------------------------
extern "C" void kernel_launch(void* const* d_in, const int* in_sizes, int n_in,
                              void* d_out, int out_size, void* d_ws, size_t ws_size,
                              hipStream_t stream)
{
    const float* coords = (const float*)d_in[0];
    const float* lat    = (const float*)d_in[1];
    const float* Wf     = (const float*)d_in[2];
    const float* bf     = (const float*)d_in[3];
    const float* Wh     = (const float*)d_in[4];
    const float* bh     = (const float*)d_in[5];
    const float* Wl     = (const float*)d_in[6];
    const float* bl     = (const float*)d_in[7];
    const float* U      = (const float*)d_in[8];
    const float* V0     = (const float*)d_in[9];
    const float* Vh     = (const float*)d_in[10];
    const float* HB     = (const float*)d_in[11];

    float* ws  = (float*)d_ws;   // ~3.07 MB
    float* ult = ws + OFS_ULT;
    float* wT  = ws + OFS_WT;
    float* dw0 = ws + OFS_DW0;
    float* fbe = ws + OFS_FBE;

    precomp_np<<<NHID * B + B + B, H, 0, stream>>>(lat, U, V0, HB, ult, dw0, fbe);
    transposeW<<<NHID * H, H, 0, stream>>>(Wh, wT);
    siren_np<<<(B * N) / PTS, BLOCK, 0, stream>>>(coords, Wf, bf, bh, Wl, bl,
                                                  wT, ult, Vh, dw0, fbe, (float*)d_out);
}

// Round 11
// 4124.169 us; speedup vs baseline: 1.0030x; 1.0030x over previous
//
#include <hip/hip_runtime.h>
#include <math.h>

// Problem constants (must match reference)
constexpr int B = 8, N = 32768, C = 3, H = 256, R = 64, NHID = 4;
constexpr int PTS   = 32;    // points per block
constexpr int BLOCK = 256;   // 32 o-lanes (8 outputs each) x 8 point-groups (4 pts each)
constexpr int PADA  = 260;   // LDS act row stride (multiple of 4 -> aligned float4)
constexpr int PADX  = 68;    // LDS XV row stride

// Workspace (floats), total ~3.07 MB:
//   ult : [NHID][B][R][H]  (U[l+1][o][r]*lat[b][r]) [r][o-PERMUTED]   = 524,288
//   wT  : [NHID][H][H]     W_hid transposed [i][o-PERMUTED]           = 262,144
//   dw0 : [B][H][3]        layer-0 dW (np-exact, materialized)        =   6,144
//   fbe : [NHID+1][B][H]   FiLM bias                                  =  10,240
// o-PERMUTATION (coalescing for o_width=8 lanes): float4-quad q of the
// canonical row is stored at position  pos4(q) = (q&1) ? 32+(q>>1) : (q>>1).
// Lane og then loads positions og and 32+og -> quads 2og, 2og+1 = outputs
// og*8..og*8+7, with 32 consecutive lanes reading 512B contiguous. Values
// are bit-exact copies; only storage order changes.
constexpr size_t OFS_ULT = 0;
constexpr size_t OFS_WT  = (size_t)NHID * B * R * H;
constexpr size_t OFS_DW0 = OFS_WT + (size_t)NHID * H * H;
constexpr size_t OFS_FBE = OFS_DW0 + (size_t)B * H * 3;

__device__ __forceinline__ int opos(int o)   // permuted float index within a row
{
    int q = o >> 2, e = o & 3;
    int p4 = (q & 1) ? (32 + (q >> 1)) : (q >> 1);
    return p4 * 4 + e;
}

// ---------------------------------------------------------------------------
// fdlibm fp64 sine, error ~1e-16. Models numpy float32 sin as
// (float)sin((double)x). Used at LAYER 0 only (error gain 6.6e4 demands it).
// ---------------------------------------------------------------------------
__device__ __forceinline__ double sin_d(double x)
{
    const double INV_PIO2 = 6.36619772367581382433e-01;
    const double P1  = 1.57079632673412561417e+00;
    const double P1T = 6.07710050650619224932e-11;
    double fn = rint(x * INV_PIO2);
    int n = (int)fn;
    double r = fma(-fn, P1, x);
    r = fma(-fn, P1T, r);
    double z = r * r;
    double ps = fma(z, 1.58969099521155010221e-10, -2.50507602534068634195e-08);
    ps = fma(z, ps, 2.75573137070700676789e-06);
    ps = fma(z, ps, -1.98412698298579493134e-04);
    ps = fma(z, ps, 8.33333333332248946124e-03);
    ps = fma(z, ps, -1.66666666666666324348e-01);
    double s = fma(r * z, ps, r);
    double pc = fma(z, -1.13596475577881948265e-11, 2.08757232129817482790e-09);
    pc = fma(z, pc, -2.75573143513906633035e-07);
    pc = fma(z, pc, 2.48015872894767294178e-05);
    pc = fma(z, pc, -1.38888888888741095749e-03);
    pc = fma(z, pc, 4.16666666666666019037e-02);
    double c = fma(z * z, pc, fma(z, -0.5, 1.0));
    int k = n & 3;
    double v = (k & 1) ? c : s;
    return (k & 2) ? -v : v;
}

__device__ __forceinline__ float npsinf(float xf)
{
    return (float)sin_d((double)xf);
}

// ---------------------------------------------------------------------------
// Hybrid sine for hidden layers: fp64 Cody-Waite argument reduction + fp32
// polynomials. Diff vs (float)sin(double) ~1 ulp fp32. (unchanged from r9/r10)
// ---------------------------------------------------------------------------
__device__ __forceinline__ float sinh32(float xf)
{
    const double INV_PIO2 = 6.36619772367581382433e-01;
    const double P1  = 1.57079632673412561417e+00;
    const double P1T = 6.07710050650619224932e-11;
    double xd = (double)xf;
    double fn = rint(xd * INV_PIO2);
    int n = (int)fn;
    double rd = fma(-fn, P1, xd);
    rd = fma(-fn, P1T, rd);
    float r = (float)rd;
    float z = r * r;
    float ps = fmaf(z, 2.7183114939898219e-06f, -1.9839334836096632e-04f);
    ps = fmaf(z, ps, 8.3333293e-03f);
    ps = fmaf(z, ps, -1.6666667e-01f);
    float s = fmaf(r * z, ps, r);
    float pc = fmaf(z, 2.4390448796277409e-05f, -1.3888781739898680e-03f);
    pc = fmaf(z, pc, 4.1666667e-02f);
    float c = fmaf(z * z, pc, fmaf(z, -0.5f, 1.0f));
    int k = n & 3;
    float v = (k & 1) ? c : s;
    return (k & 2) ? -v : v;
}

// ---------------------------------------------------------------------------
// Precompute: ult[l][b][r][opos(o)] = U[l+1][o][r]*lat[b][r]  (permuted store),
// dw0 (layer-0 dW, np-exact), fbe (FiLM bias). Values identical to r9/r10.
// ---------------------------------------------------------------------------
__global__ void precomp_np(const float* __restrict__ lat, const float* __restrict__ U,
                           const float* __restrict__ V0,
                           const float* __restrict__ HB,
                           float* __restrict__ ult, float* __restrict__ dw0,
                           float* __restrict__ fbe)
{
    int bi = blockIdx.x;
    int o  = threadIdx.x;
    if (bi < NHID * B) {
        int l = bi >> 3, b = bi & 7;
        const float* Uo = U + ((size_t)(l + 1) * H + o) * R;
        const float* lb = lat + b * R;
        float* dst = ult + (size_t)(l * B + b) * R * H;   // [r][opos]
        const int op = opos(o);
        #pragma unroll
        for (int r = 0; r < R; ++r)
            dst[(size_t)r * H + op] = Uo[r] * lb[r];      // rounded fp32 mul (np order)
    } else if (bi < NHID * B + B) {
        int b = bi - NHID * B;
        const float* Uo = U + (size_t)o * R;        // U[0][o][:]
        const float* lb = lat + b * R;
        float t[R];
        #pragma unroll
        for (int r = 0; r < R; ++r) t[r] = Uo[r] * lb[r];
        #pragma unroll
        for (int c = 0; c < C; ++c) {
            float acc = 0.f;
            #pragma unroll
            for (int r = 0; r < R; ++r) acc = fmaf(t[r], V0[c * R + r], acc);
            dw0[((size_t)b * H + o) * 3 + c] = acc;
        }
    } else {
        int b = bi - NHID * B - B;
        const float* lb = lat + b * R;
        for (int lidx = 0; lidx < NHID + 1; ++lidx) {
            const float* hb = HB + ((size_t)lidx * H + o) * R;
            float acc = 0.f;
            #pragma unroll
            for (int r = 0; r < R; ++r) acc = fmaf(lb[r], hb[r], acc);
            fbe[((size_t)lidx * B + b) * H + o] = acc;
        }
    }
}

// Bit-exact transpose with o-permuted columns: wT[l][i][opos(o)] = W_hid[l][o][i]
__global__ void transposeW(const float* __restrict__ Wh, float* __restrict__ wT)
{
    int li = blockIdx.x;           // l*H + i
    int o  = threadIdx.x;
    int l = li >> 8, i = li & 255;
    wT[(size_t)li * H + opos(o)] = Wh[((size_t)l * H + o) * H + i];
}

// ---------------------------------------------------------------------------
// np-replica forward, o_width=8 mapping (halved act DS traffic vs r9) with
// COALESCED permuted weight loads: lane og reads float4 positions og and
// 32+og of each row (contiguous 512B per 32 lanes). Per-(n,o) arithmetic
// BIT-IDENTICAL to rounds 6-10: lin = single fp32 acc, i ascending, fmaf;
// delta factored (XV then ult, r ascending); ((lin+b)+delta)+fb, *30.0f,
// sin (L0 fp64, hidden hybrid).
// ---------------------------------------------------------------------------
__launch_bounds__(BLOCK)
__global__ void siren_np(const float* __restrict__ coords,
                         const float* __restrict__ Wf, const float* __restrict__ bf,
                         const float* __restrict__ bh,
                         const float* __restrict__ Wl, const float* __restrict__ bl,
                         const float* __restrict__ wT, const float* __restrict__ ult,
                         const float* __restrict__ Vh,
                         const float* __restrict__ dw0, const float* __restrict__ fbe,
                         float* __restrict__ out)
{
    __shared__ __align__(16) float abuf[PTS * PADA];   // 33,280 B
    __shared__ __align__(16) float xvbuf[PTS * PADX];  //  8,704 B
    __shared__ float cbuf[PTS * 3 + 1];
    const int tid = threadIdx.x;
    const int og = tid & 31, pg = tid >> 5;
    const int o0 = og * 8, pbase = pg * 4;
    const int p0 = blockIdx.x * PTS;          // global point base
    const int b  = p0 >> 15;                  // N = 2^15; all 32 pts same batch

    if (tid < PTS * 3) cbuf[tid] = coords[(size_t)p0 * 3 + tid];
    __syncthreads();

    // ---- layer 0 (same per-(n,o) arithmetic as rounds 6-10) ----
    {
        const float* fb0 = fbe + (size_t)(0 * B + b) * H;
        #pragma unroll
        for (int j = 0; j < 8; ++j) {
            const int o = o0 + j;
            const float wf0 = Wf[o * 3 + 0], wf1 = Wf[o * 3 + 1], wf2 = Wf[o * 3 + 2];
            const float* dwo = dw0 + ((size_t)b * H + o) * 3;
            const float dd0 = dwo[0], dd1 = dwo[1], dd2 = dwo[2];
            const float bo = bf[o], fo = fb0[o];
            #pragma unroll
            for (int k = 0; k < 4; ++k) {
                const float x0 = cbuf[(pbase + k) * 3 + 0];
                const float x1 = cbuf[(pbase + k) * 3 + 1];
                const float x2 = cbuf[(pbase + k) * 3 + 2];
                float lin = 0.f;
                lin = fmaf(x0, wf0, lin);
                lin = fmaf(x1, wf1, lin);
                lin = fmaf(x2, wf2, lin);
                lin = lin + bo;
                float dl = 0.f;
                dl = fmaf(x0, dd0, dl);
                dl = fmaf(x1, dd1, dl);
                dl = fmaf(x2, dd2, dl);
                float z = (lin + dl) + fo;
                abuf[(pbase + k) * PADA + o] = npsinf(30.0f * z);
            }
        }
    }
    __syncthreads();

    // ---- hidden layers ----
    for (int l = 0; l < NHID; ++l) {
        // phase A (unchanged): XV[n][r] = sum_i act[n][i]*V[l][i][r]
        {
            const int xn = tid >> 3, r0 = (tid & 7) * 8;
            const float* Vb = Vh + (size_t)l * H * R;     // [i][r]
            float a8[8] = {0.f,0.f,0.f,0.f,0.f,0.f,0.f,0.f};
            for (int i0 = 0; i0 < H; i0 += 4) {
                float4 a4 = *(const float4*)(&abuf[xn * PADA + i0]);
                #pragma unroll
                for (int ii = 0; ii < 4; ++ii) {
                    const float ai = (&a4.x)[ii];
                    float4 va = *(const float4*)(Vb + (size_t)(i0 + ii) * R + r0);
                    float4 vb = *(const float4*)(Vb + (size_t)(i0 + ii) * R + r0 + 4);
                    a8[0] = fmaf(ai, va.x, a8[0]); a8[1] = fmaf(ai, va.y, a8[1]);
                    a8[2] = fmaf(ai, va.z, a8[2]); a8[3] = fmaf(ai, va.w, a8[3]);
                    a8[4] = fmaf(ai, vb.x, a8[4]); a8[5] = fmaf(ai, vb.y, a8[5]);
                    a8[6] = fmaf(ai, vb.z, a8[6]); a8[7] = fmaf(ai, vb.w, a8[7]);
                }
            }
            *(float4*)(&xvbuf[xn * PADX + r0])     = make_float4(a8[0], a8[1], a8[2], a8[3]);
            *(float4*)(&xvbuf[xn * PADX + r0 + 4]) = make_float4(a8[4], a8[5], a8[6], a8[7]);
        }
        __syncthreads();

        // phase B: delta (K=64 over permuted ult, r ascending) ...
        float eacc[8][4];
        #pragma unroll
        for (int j = 0; j < 8; ++j)
            #pragma unroll
            for (int k = 0; k < 4; ++k) eacc[j][k] = 0.f;
        {
            const float4* UT4 = (const float4*)(ult + (size_t)(l * B + b) * R * H);
            for (int r0 = 0; r0 < R; r0 += 4) {
                float4 xv4[4];
                #pragma unroll
                for (int k = 0; k < 4; ++k)
                    xv4[k] = *(const float4*)(&xvbuf[(pbase + k) * PADX + r0]);
                #pragma unroll
                for (int rr = 0; rr < 4; ++rr) {       // r ASCENDING
                    const float4 ua = UT4[(size_t)(r0 + rr) * 64 + og];        // quads 2og
                    const float4 ub = UT4[(size_t)(r0 + rr) * 64 + 32 + og];   // quad 2og+1
                    const float uj[8] = {ua.x, ua.y, ua.z, ua.w, ub.x, ub.y, ub.z, ub.w};
                    #pragma unroll
                    for (int k = 0; k < 4; ++k) {
                        const float xv = (&xv4[k].x)[rr];
                        #pragma unroll
                        for (int j = 0; j < 8; ++j)
                            eacc[j][k] = fmaf(xv, uj[j], eacc[j][k]);
                    }
                }
            }
        }
        // ... then lin (K=256 over np-exact permuted wT, i ascending, single acc)
        float lacc[8][4];
        #pragma unroll
        for (int j = 0; j < 8; ++j)
            #pragma unroll
            for (int k = 0; k < 4; ++k) lacc[j][k] = 0.f;
        {
            const float4* Wt4 = (const float4*)(wT + (size_t)l * H * H);
            for (int i0 = 0; i0 < H; i0 += 4) {
                float4 av[4];
                #pragma unroll
                for (int k = 0; k < 4; ++k)
                    av[k] = *(const float4*)(&abuf[(pbase + k) * PADA + i0]);
                #pragma unroll
                for (int ii = 0; ii < 4; ++ii) {        // i ASCENDING (np sgemm)
                    const int i = i0 + ii;
                    const float4 wa = Wt4[(size_t)i * 64 + og];        // coalesced 512B
                    const float4 wb = Wt4[(size_t)i * 64 + 32 + og];   // coalesced 512B
                    const float wj[8] = {wa.x, wa.y, wa.z, wa.w, wb.x, wb.y, wb.z, wb.w};
                    #pragma unroll
                    for (int k = 0; k < 4; ++k) {
                        const float ai = (&av[k].x)[ii];
                        #pragma unroll
                        for (int j = 0; j < 8; ++j)
                            lacc[j][k] = fmaf(ai, wj[j], lacc[j][k]);
                    }
                }
            }
        }
        __syncthreads();   // ALL reads of abuf/xvbuf complete before in-place writes
        {
            const float* be  = bh + (size_t)l * H;
            const float* fbl = fbe + (size_t)((l + 1) * B + b) * H;
            const float4 bo4a = *(const float4*)(be + o0);
            const float4 bo4b = *(const float4*)(be + o0 + 4);
            const float4 fo4a = *(const float4*)(fbl + o0);
            const float4 fo4b = *(const float4*)(fbl + o0 + 4);
            const float bo[8] = {bo4a.x, bo4a.y, bo4a.z, bo4a.w,
                                 bo4b.x, bo4b.y, bo4b.z, bo4b.w};
            const float fo[8] = {fo4a.x, fo4a.y, fo4a.z, fo4a.w,
                                 fo4b.x, fo4b.y, fo4b.z, fo4b.w};
            #pragma unroll
            for (int k = 0; k < 4; ++k) {
                float4 rv0, rv1;
                #pragma unroll
                for (int j = 0; j < 8; ++j) {
                    float z = ((lacc[j][k] + bo[j]) + eacc[j][k]) + fo[j];
                    float sv = sinh32(30.0f * z);
                    if (j < 4) (&rv0.x)[j] = sv; else (&rv1.x)[j - 4] = sv;
                }
                *(float4*)(&abuf[(pbase + k) * PADA + o0])     = rv0;
                *(float4*)(&abuf[(pbase + k) * PADA + o0 + 4]) = rv1;
            }
        }
        __syncthreads();   // writes visible before next layer's reads
    }

    // ---- final projection (gain ~1): same arithmetic as rounds 6-10 ----
    {
        const int pl = tid >> 3, q = tid & 7;
        const float* ar = abuf + pl * PADA + q * 32;
        const float* wl = Wl + q * 32;
        float s = 0.f;
        #pragma unroll 8
        for (int t = 0; t < 32; ++t) s = fmaf(ar[t], wl[t], s);
        s += __shfl_xor(s, 1);
        s += __shfl_xor(s, 2);
        s += __shfl_xor(s, 4);
        if (q == 0) out[p0 + pl] = s + bl[0];
    }
}

// ---------------------------------------------------------------------------
extern "C" void kernel_launch(void* const* d_in, const int* in_sizes, int n_in,
                              void* d_out, int out_size, void* d_ws, size_t ws_size,
                              hipStream_t stream)
{
    const float* coords = (const float*)d_in[0];
    const float* lat    = (const float*)d_in[1];
    const float* Wf     = (const float*)d_in[2];
    const float* bf     = (const float*)d_in[3];
    const float* Wh     = (const float*)d_in[4];
    const float* bh     = (const float*)d_in[5];
    const float* Wl     = (const float*)d_in[6];
    const float* bl     = (const float*)d_in[7];
    const float* U      = (const float*)d_in[8];
    const float* V0     = (const float*)d_in[9];
    const float* Vh     = (const float*)d_in[10];
    const float* HB     = (const float*)d_in[11];

    float* ws  = (float*)d_ws;   // ~3.07 MB
    float* ult = ws + OFS_ULT;
    float* wT  = ws + OFS_WT;
    float* dw0 = ws + OFS_DW0;
    float* fbe = ws + OFS_FBE;

    precomp_np<<<NHID * B + B + B, H, 0, stream>>>(lat, U, V0, HB, ult, dw0, fbe);
    transposeW<<<NHID * H, H, 0, stream>>>(Wh, wT);
    siren_np<<<(B * N) / PTS, BLOCK, 0, stream>>>(coords, Wf, bf, bh, Wl, bl,
                                                  wT, ult, Vh, dw0, fbe, (float*)d_out);
}

// Round 12
// 3356.255 us; speedup vs baseline: 1.2325x; 1.2288x over previous
//
#include <hip/hip_runtime.h>
#include <math.h>

// Problem constants (must match reference)
constexpr int B = 8, N = 32768, C = 3, H = 256, R = 64, NHID = 4;
constexpr int PTS   = 64;    // points per block
constexpr int BLOCK = 256;   // 64 o-lanes (4 outputs each) x 4 point-groups (16 pts each)
constexpr int PADA  = 260;   // LDS act row stride (multiple of 4 -> aligned float4)

// Workspace (floats), total ~9.46 MB (r7/r8 layout, proven):
//   dwT : [NHID][B][H][H]  dW transposed [i][o]  (np-exact values)  = 2,097,152
//   wT  : [NHID][H][H]     W_hid transposed [i][o] (bit-exact copy) =   262,144
//   dw0 : [B][H][3]        layer-0 dW                               =     6,144
//   fbe : [NHID+1][B][H]   FiLM bias                                =    10,240
constexpr size_t OFS_DWT = 0;
constexpr size_t OFS_WT  = (size_t)NHID * B * H * H;
constexpr size_t OFS_DW0 = OFS_WT + (size_t)NHID * H * H;
constexpr size_t OFS_FBE = OFS_DW0 + (size_t)B * H * 3;

// ---------------------------------------------------------------------------
// fdlibm fp64 sine, error ~1e-16. Models numpy float32 sin as
// (float)sin((double)x). Used at LAYER 0 only (error gain 6.6e4 demands it).
// ---------------------------------------------------------------------------
__device__ __forceinline__ double sin_d(double x)
{
    const double INV_PIO2 = 6.36619772367581382433e-01;
    const double P1  = 1.57079632673412561417e+00;
    const double P1T = 6.07710050650619224932e-11;
    double fn = rint(x * INV_PIO2);
    int n = (int)fn;
    double r = fma(-fn, P1, x);
    r = fma(-fn, P1T, r);
    double z = r * r;
    double ps = fma(z, 1.58969099521155010221e-10, -2.50507602534068634195e-08);
    ps = fma(z, ps, 2.75573137070700676789e-06);
    ps = fma(z, ps, -1.98412698298579493134e-04);
    ps = fma(z, ps, 8.33333333332248946124e-03);
    ps = fma(z, ps, -1.66666666666666324348e-01);
    double s = fma(r * z, ps, r);
    double pc = fma(z, -1.13596475577881948265e-11, 2.08757232129817482790e-09);
    pc = fma(z, pc, -2.75573143513906633035e-07);
    pc = fma(z, pc, 2.48015872894767294178e-05);
    pc = fma(z, pc, -1.38888888888741095749e-03);
    pc = fma(z, pc, 4.16666666666666019037e-02);
    double c = fma(z * z, pc, fma(z, -0.5, 1.0));
    int k = n & 3;
    double v = (k & 1) ? c : s;
    return (k & 2) ? -v : v;
}

__device__ __forceinline__ float npsinf(float xf)
{
    return (float)sin_d((double)xf);
}

// ---------------------------------------------------------------------------
// Hybrid sine for hidden layers (r9-proven): fp64 Cody-Waite reduction +
// fp32 polynomials; ~1 ulp fp32 vs (float)sin(double).
// ---------------------------------------------------------------------------
__device__ __forceinline__ float sinh32(float xf)
{
    const double INV_PIO2 = 6.36619772367581382433e-01;
    const double P1  = 1.57079632673412561417e+00;
    const double P1T = 6.07710050650619224932e-11;
    double xd = (double)xf;
    double fn = rint(xd * INV_PIO2);
    int n = (int)fn;
    double rd = fma(-fn, P1, xd);
    rd = fma(-fn, P1T, rd);
    float r = (float)rd;
    float z = r * r;
    float ps = fmaf(z, 2.7183114939898219e-06f, -1.9839334836096632e-04f);
    ps = fmaf(z, ps, 8.3333293e-03f);
    ps = fmaf(z, ps, -1.6666667e-01f);
    float s = fmaf(r * z, ps, r);
    float pc = fmaf(z, 2.4390448796277409e-05f, -1.3888781739898680e-03f);
    pc = fmaf(z, pc, 4.1666667e-02f);
    float c = fmaf(z * z, pc, fmaf(z, -0.5f, 1.0f));
    int k = n & 3;
    float v = (k & 1) ? c : s;
    return (k & 2) ? -v : v;
}

// ---------------------------------------------------------------------------
// Materialize np's fp32 intermediates EXACTLY (r7/r8 code, proven bit-exact):
//   dW[l][b][o][i] = sum_r (U[l+1][o][r]*lat[b][r]) * V[l][i][r], stored [i][o]
// ---------------------------------------------------------------------------
__global__ void precomp_np(const float* __restrict__ lat, const float* __restrict__ U,
                           const float* __restrict__ V0,  const float* __restrict__ Vh,
                           const float* __restrict__ HB,
                           float* __restrict__ dwT, float* __restrict__ dw0,
                           float* __restrict__ fbe)
{
    int bi = blockIdx.x;
    int o  = threadIdx.x;
    if (bi < NHID * B) {
        int l = bi >> 3, b = bi & 7;
        const float* Uo = U + ((size_t)(l + 1) * H + o) * R;
        const float* lb = lat + b * R;
        float t[R];
        #pragma unroll
        for (int r = 0; r < R; ++r) t[r] = Uo[r] * lb[r];   // rounded fp32 mul
        const float* Vb = Vh + (size_t)l * H * R;
        float* dst = dwT + (size_t)(l * B + b) * H * H;     // [i][o]
        for (int i = 0; i < H; ++i) {
            const float* Vi = Vb + (size_t)i * R;
            float acc = 0.f;
            #pragma unroll
            for (int r = 0; r < R; ++r) acc = fmaf(t[r], Vi[r], acc);
            dst[(size_t)i * H + o] = acc;                   // coalesced over o
        }
    } else if (bi < NHID * B + B) {
        int b = bi - NHID * B;
        const float* Uo = U + (size_t)o * R;        // U[0][o][:]
        const float* lb = lat + b * R;
        float t[R];
        #pragma unroll
        for (int r = 0; r < R; ++r) t[r] = Uo[r] * lb[r];
        #pragma unroll
        for (int c = 0; c < C; ++c) {
            float acc = 0.f;
            #pragma unroll
            for (int r = 0; r < R; ++r) acc = fmaf(t[r], V0[c * R + r], acc);
            dw0[((size_t)b * H + o) * 3 + c] = acc;
        }
    } else {
        int b = bi - NHID * B - B;
        const float* lb = lat + b * R;
        for (int lidx = 0; lidx < NHID + 1; ++lidx) {
            const float* hb = HB + ((size_t)lidx * H + o) * R;
            float acc = 0.f;
            #pragma unroll
            for (int r = 0; r < R; ++r) acc = fmaf(lb[r], hb[r], acc);
            fbe[((size_t)lidx * B + b) * H + o] = acc;
        }
    }
}

// Pure bit-exact transpose: wT[l][i][o] = W_hid[l][o][i]
__global__ void transposeW(const float* __restrict__ Wh, float* __restrict__ wT)
{
    int li = blockIdx.x;           // l*H + i
    int o  = threadIdx.x;
    int l = li >> 8, i = li & 255;
    wT[(size_t)li * H + o] = Wh[((size_t)l * H + o) * H + i];
}

// ---------------------------------------------------------------------------
// np-replica forward, o4 x k16 tile (PTS=64): halves L1 bytes/FMA and DS
// instr/FMA vs r9's o4 x k8 -> VALU becomes the sole bottleneck.
// og=tid&63 owns 4 outputs (weight loads = one fully-coalesced 1KB wave
// instruction per row per stream); pg=tid>>6 owns 16 points (act reads =
// wave-wide broadcast b128). Per-(n,o) arithmetic BIT-IDENTICAL to r8:
// lin and delta each = single fp32 acc, i ascending, fmaf over np-exact
// wT/dwT; ((lin+b)+delta)+fb, *30.0f, sin (L0 fp64, hidden hybrid=r9).
// ---------------------------------------------------------------------------
__launch_bounds__(BLOCK)
__global__ void siren_np(const float* __restrict__ coords,
                         const float* __restrict__ Wf, const float* __restrict__ bf,
                         const float* __restrict__ bh,
                         const float* __restrict__ Wl, const float* __restrict__ bl,
                         const float* __restrict__ wT, const float* __restrict__ dwT,
                         const float* __restrict__ dw0, const float* __restrict__ fbe,
                         float* __restrict__ out)
{
    __shared__ __align__(16) float abuf[PTS * PADA];   // 66,560 B -> 2 blocks/CU
    __shared__ float cbuf[PTS * 3 + 1];
    const int tid = threadIdx.x;
    const int og = tid & 63, pg = tid >> 6;
    const int o0 = og * 4, pbase = pg * 16;
    const int p0 = blockIdx.x * PTS;          // global point base
    const int b  = p0 >> 15;                  // N = 2^15; all 64 pts same batch

    if (tid < PTS * 3) cbuf[tid] = coords[(size_t)p0 * 3 + tid];
    __syncthreads();

    // ---- layer 0 (same per-(n,o) arithmetic as rounds 6-11) ----
    {
        const float* fb0 = fbe + (size_t)(0 * B + b) * H;
        #pragma unroll
        for (int j = 0; j < 4; ++j) {
            const int o = o0 + j;
            const float wf0 = Wf[o * 3 + 0], wf1 = Wf[o * 3 + 1], wf2 = Wf[o * 3 + 2];
            const float* dwo = dw0 + ((size_t)b * H + o) * 3;
            const float dd0 = dwo[0], dd1 = dwo[1], dd2 = dwo[2];
            const float bo = bf[o], fo = fb0[o];
            for (int k = 0; k < 16; ++k) {
                const float x0 = cbuf[(pbase + k) * 3 + 0];
                const float x1 = cbuf[(pbase + k) * 3 + 1];
                const float x2 = cbuf[(pbase + k) * 3 + 2];
                float lin = 0.f;
                lin = fmaf(x0, wf0, lin);
                lin = fmaf(x1, wf1, lin);
                lin = fmaf(x2, wf2, lin);
                lin = lin + bo;
                float dl = 0.f;
                dl = fmaf(x0, dd0, dl);
                dl = fmaf(x1, dd1, dl);
                dl = fmaf(x2, dd2, dl);
                float z = (lin + dl) + fo;
                abuf[(pbase + k) * PADA + o] = npsinf(30.0f * z);
            }
        }
    }
    __syncthreads();

    // ---- hidden layers (single abuf; read-all / barrier / write-in-place) ----
    for (int l = 0; l < NHID; ++l) {
        const float4* Wt4 = (const float4*)(wT  + (size_t)l * H * H);
        const float4* Dt4 = (const float4*)(dwT + (size_t)(l * B + b) * H * H);

        float lacc[4][16], eacc[4][16];
        #pragma unroll
        for (int j = 0; j < 4; ++j)
            #pragma unroll
            for (int k = 0; k < 16; ++k) { lacc[j][k] = 0.f; eacc[j][k] = 0.f; }

        for (int i0 = 0; i0 < H; i0 += 4) {
            // weight rows for this step: 8 fully-coalesced 1KB wave loads
            float4 w4[4], d4[4];
            #pragma unroll
            for (int ii = 0; ii < 4; ++ii) {
                w4[ii] = Wt4[(size_t)(i0 + ii) * 64 + og];
                d4[ii] = Dt4[(size_t)(i0 + ii) * 64 + og];
            }
            // act tiles: 16 broadcast b128 reads
            float4 av[16];
            #pragma unroll
            for (int k = 0; k < 16; ++k)
                av[k] = *(const float4*)(&abuf[(pbase + k) * PADA + i0]);
            #pragma unroll
            for (int ii = 0; ii < 4; ++ii) {        // i ASCENDING (np sgemm)
                const float wj[4] = {w4[ii].x, w4[ii].y, w4[ii].z, w4[ii].w};
                const float dj[4] = {d4[ii].x, d4[ii].y, d4[ii].z, d4[ii].w};
                #pragma unroll
                for (int k = 0; k < 16; ++k) {
                    const float ai = (&av[k].x)[ii];
                    #pragma unroll
                    for (int j = 0; j < 4; ++j) {
                        lacc[j][k] = fmaf(ai, wj[j], lacc[j][k]);
                        eacc[j][k] = fmaf(ai, dj[j], eacc[j][k]);
                    }
                }
            }
        }
        __syncthreads();   // ALL reads of abuf complete before in-place writes
        {
            const float* be  = bh + (size_t)l * H;
            const float* fbl = fbe + (size_t)((l + 1) * B + b) * H;
            const float4 bo4 = *(const float4*)(be + o0);
            const float4 fo4 = *(const float4*)(fbl + o0);
            const float bo[4] = {bo4.x, bo4.y, bo4.z, bo4.w};
            const float fo[4] = {fo4.x, fo4.y, fo4.z, fo4.w};
            for (int k = 0; k < 16; ++k) {
                float4 rv;
                #pragma unroll
                for (int j = 0; j < 4; ++j) {
                    float z = ((lacc[j][k] + bo[j]) + eacc[j][k]) + fo[j];
                    (&rv.x)[j] = sinh32(30.0f * z);
                }
                *(float4*)(&abuf[(pbase + k) * PADA + o0]) = rv;
            }
        }
        __syncthreads();   // writes visible before next layer's reads
    }

    // ---- final projection (gain ~1) ----
    {
        const int n = tid >> 2, q = tid & 3;      // 4 threads cooperate per point
        const float* ar = abuf + n * PADA + q * 64;
        const float* wl = Wl + q * 64;
        float s = 0.f;
        #pragma unroll 16
        for (int t = 0; t < 64; ++t) s = fmaf(ar[t], wl[t], s);
        s += __shfl_xor(s, 1);
        s += __shfl_xor(s, 2);
        if (q == 0) out[p0 + n] = s + bl[0];
    }
}

// ---------------------------------------------------------------------------
extern "C" void kernel_launch(void* const* d_in, const int* in_sizes, int n_in,
                              void* d_out, int out_size, void* d_ws, size_t ws_size,
                              hipStream_t stream)
{
    const float* coords = (const float*)d_in[0];
    const float* lat    = (const float*)d_in[1];
    const float* Wf     = (const float*)d_in[2];
    const float* bf     = (const float*)d_in[3];
    const float* Wh     = (const float*)d_in[4];
    const float* bh     = (const float*)d_in[5];
    const float* Wl     = (const float*)d_in[6];
    const float* bl     = (const float*)d_in[7];
    const float* U      = (const float*)d_in[8];
    const float* V0     = (const float*)d_in[9];
    const float* Vh     = (const float*)d_in[10];
    const float* HB     = (const float*)d_in[11];

    float* ws  = (float*)d_ws;   // ~9.46 MB
    float* dwT = ws + OFS_DWT;
    float* wT  = ws + OFS_WT;
    float* dw0 = ws + OFS_DW0;
    float* fbe = ws + OFS_FBE;

    precomp_np<<<NHID * B + B + B, H, 0, stream>>>(lat, U, V0, Vh, HB, dwT, dw0, fbe);
    transposeW<<<NHID * H, H, 0, stream>>>(Wh, wT);
    siren_np<<<(B * N) / PTS, BLOCK, 0, stream>>>(coords, Wf, bf, bh, Wl, bl,
                                                  wT, dwT, dw0, fbe, (float*)d_out);
}